// Round 1
// baseline (151.567 us; speedup 1.0000x reference)
//
#include <hip/hip_runtime.h>

#define D_ 8
#define B_ 32
#define PRE_ 1024
#define POST_ 1024

// exp(-1/10), exp(-1/20), exp(-1/15)
#define ALPHA_P 0.90483741803595952f
#define ALPHA_D 0.95122942450071400f
#define ALPHA_X 0.93550698503161731f

// Main kernel: one block per e (PRE), 256 threads, each thread owns 4 contiguous o.
// dmap[d][e][o..o+3] is held in registers across the b-loop -> dmap read from HBM once.
__global__ __launch_bounds__(256) void clopath_main(
    const float* __restrict__ W,
    const float* __restrict__ dmap,
    const float* __restrict__ A_p,
    const float* __restrict__ A_d,
    const float* __restrict__ wmax,
    const float* __restrict__ xbar_pre,
    const float* __restrict__ Xd,
    const float* __restrict__ Xpost,
    const float* __restrict__ u_pot,
    const float* __restrict__ u_dep,
    float* __restrict__ out,     // output 0: copy of W
    float* __restrict__ W_new)   // output 1
{
    const int e   = blockIdx.x;          // 0..1023
    const int tid = threadIdx.x;         // 0..255
    const int o   = tid << 2;            // float4 of POST

    // Stage the block-uniform scalars xbar_pre[d,b,e], Xd[d,b,e] (t = d*B+b, 256 values)
    __shared__ float xb_lds[D_ * B_];
    __shared__ float xd_lds[D_ * B_];
    xb_lds[tid] = xbar_pre[(size_t)tid * PRE_ + e];
    xd_lds[tid] = Xd[(size_t)tid * PRE_ + e];
    __syncthreads();

    // Preload dmap rows and per-(e,o) factors into registers
    float dmv[D_][4];
    #pragma unroll
    for (int d = 0; d < D_; ++d) {
        float4 t = *reinterpret_cast<const float4*>(
            dmap + ((size_t)(d * PRE_ + e) * POST_ + o));
        dmv[d][0] = t.x; dmv[d][1] = t.y; dmv[d][2] = t.z; dmv[d][3] = t.w;
    }
    float apv[4], adv[4], wmv[4];
    {
        float4 a = *reinterpret_cast<const float4*>(A_p  + ((size_t)e * POST_ + o));
        apv[0] = a.x; apv[1] = a.y; apv[2] = a.z; apv[3] = a.w;
        float4 b = *reinterpret_cast<const float4*>(A_d  + ((size_t)e * POST_ + o));
        adv[0] = b.x; adv[1] = b.y; adv[2] = b.z; adv[3] = b.w;
        float4 c = *reinterpret_cast<const float4*>(wmax + ((size_t)e * POST_ + o));
        wmv[0] = c.x; wmv[1] = c.y; wmv[2] = c.z; wmv[3] = c.w;
    }

    for (int b = 0; b < B_; ++b) {
        const size_t wi = ((size_t)(b * PRE_ + e)) * POST_ + o;
        const size_t go = (size_t)b * POST_ + o;

        float4 w4  = *reinterpret_cast<const float4*>(W      + wi);
        float4 xp4 = *reinterpret_cast<const float4*>(Xpost  + go);
        float4 up4 = *reinterpret_cast<const float4*>(u_pot  + go);
        float4 ud4 = *reinterpret_cast<const float4*>(u_dep  + go);

        float wv[4] = {w4.x, w4.y, w4.z, w4.w};
        float xpv[4] = {xp4.x, xp4.y, xp4.z, xp4.w};
        float upv[4] = {up4.x, up4.y, up4.z, up4.w};
        float udv[4] = {ud4.x, ud4.y, ud4.z, ud4.w};

        // S_pot = sum_d xbar[d,b,e]*dmap[d,e,o] ; S_dep = sum_d Xd[d,b,e]*dmap[d,e,o]
        float sp[4] = {0.f, 0.f, 0.f, 0.f};
        float sd[4] = {0.f, 0.f, 0.f, 0.f};
        #pragma unroll
        for (int d = 0; d < D_; ++d) {
            const float xb = xb_lds[d * B_ + b];   // uniform address -> LDS broadcast
            const float xd = xd_lds[d * B_ + b];
            #pragma unroll
            for (int j = 0; j < 4; ++j) {
                sp[j] = fmaf(xb, dmv[d][j], sp[j]);
                sd[j] = fmaf(xd, dmv[d][j], sd[j]);
            }
        }

        float ov[4], nv[4];
        #pragma unroll
        for (int j = 0; j < 4; ++j) {
            const float gp = xpv[j] * fmaxf(upv[j], 0.f);  // Xpost * relu(u_pot)
            const float gd = fmaxf(udv[j], 0.f);           // relu(u_dep)
            float wn = wv[j] + sp[j] * apv[j] * gp - sd[j] * adv[j] * gd;
            wn = fminf(wmv[j], fmaxf(wn, 0.f));
            ov[j] = wv[j];
            nv[j] = wn;
        }
        *reinterpret_cast<float4*>(out   + wi) = make_float4(ov[0], ov[1], ov[2], ov[3]);
        *reinterpret_cast<float4*>(W_new + wi) = make_float4(nv[0], nv[1], nv[2], nv[3]);
    }
}

// Elementwise exponential-filter outputs: xbar_pre_new (262144), u_pot_new, u_dep_new (32768 each)
__global__ __launch_bounds__(256) void clopath_filters(
    const float* __restrict__ xbar_pre,
    const float* __restrict__ Xd,
    const float* __restrict__ Vpost,
    const float* __restrict__ u_pot,
    const float* __restrict__ u_dep,
    float* __restrict__ xbar_new,
    float* __restrict__ u_pot_new,
    float* __restrict__ u_dep_new)
{
    const int i = blockIdx.x * blockDim.x + threadIdx.x;   // float4 index
    const int NX = (D_ * B_ * PRE_) / 4;   // 65536
    const int NU = (B_ * POST_) / 4;       // 8192

    if (i < NX) {
        float4 a = *reinterpret_cast<const float4*>(xbar_pre + (size_t)i * 4);
        float4 b = *reinterpret_cast<const float4*>(Xd       + (size_t)i * 4);
        float4 r;
        r.x = ALPHA_X * a.x + (1.0f - ALPHA_X) * b.x;
        r.y = ALPHA_X * a.y + (1.0f - ALPHA_X) * b.y;
        r.z = ALPHA_X * a.z + (1.0f - ALPHA_X) * b.z;
        r.w = ALPHA_X * a.w + (1.0f - ALPHA_X) * b.w;
        *reinterpret_cast<float4*>(xbar_new + (size_t)i * 4) = r;
    } else if (i < NX + NU) {
        const int j = i - NX;
        float4 a = *reinterpret_cast<const float4*>(u_pot + (size_t)j * 4);
        float4 b = *reinterpret_cast<const float4*>(Vpost + (size_t)j * 4);
        float4 r;
        r.x = ALPHA_P * a.x + (1.0f - ALPHA_P) * b.x;
        r.y = ALPHA_P * a.y + (1.0f - ALPHA_P) * b.y;
        r.z = ALPHA_P * a.z + (1.0f - ALPHA_P) * b.z;
        r.w = ALPHA_P * a.w + (1.0f - ALPHA_P) * b.w;
        *reinterpret_cast<float4*>(u_pot_new + (size_t)j * 4) = r;
    } else {
        const int j = i - NX - NU;
        float4 a = *reinterpret_cast<const float4*>(u_dep + (size_t)j * 4);
        float4 b = *reinterpret_cast<const float4*>(Vpost + (size_t)j * 4);
        float4 r;
        r.x = ALPHA_D * a.x + (1.0f - ALPHA_D) * b.x;
        r.y = ALPHA_D * a.y + (1.0f - ALPHA_D) * b.y;
        r.z = ALPHA_D * a.z + (1.0f - ALPHA_D) * b.z;
        r.w = ALPHA_D * a.w + (1.0f - ALPHA_D) * b.w;
        *reinterpret_cast<float4*>(u_dep_new + (size_t)j * 4) = r;
    }
}

extern "C" void kernel_launch(void* const* d_in, const int* in_sizes, int n_in,
                              void* d_out, int out_size, void* d_ws, size_t ws_size,
                              hipStream_t stream) {
    const float* Xd       = (const float*)d_in[0];
    const float* Xpost    = (const float*)d_in[1];
    const float* Vpost    = (const float*)d_in[2];
    const float* W        = (const float*)d_in[3];
    const float* xbar_pre = (const float*)d_in[4];
    const float* u_pot    = (const float*)d_in[5];
    const float* u_dep    = (const float*)d_in[6];
    const float* dmap     = (const float*)d_in[7];
    const float* A_p      = (const float*)d_in[8];
    const float* A_d      = (const float*)d_in[9];
    const float* wmax     = (const float*)d_in[10];

    float* out        = (float*)d_out;
    float* W_new      = out + (size_t)B_ * PRE_ * POST_;         // 33,554,432
    float* xbar_new   = W_new + (size_t)B_ * PRE_ * POST_;       // +33,554,432
    float* u_pot_new  = xbar_new + (size_t)D_ * B_ * PRE_;       // +262,144
    float* u_dep_new  = u_pot_new + (size_t)B_ * POST_;          // +32,768

    clopath_main<<<PRE_, 256, 0, stream>>>(
        W, dmap, A_p, A_d, wmax, xbar_pre, Xd, Xpost, u_pot, u_dep, out, W_new);

    const int n4 = (D_ * B_ * PRE_) / 4 + 2 * ((B_ * POST_) / 4);  // 81920
    clopath_filters<<<(n4 + 255) / 256, 256, 0, stream>>>(
        xbar_pre, Xd, Vpost, u_pot, u_dep, xbar_new, u_pot_new, u_dep_new);
}

// Round 2
// 140.620 us; speedup vs baseline: 1.0778x; 1.0778x over previous
//
#include <hip/hip_runtime.h>

#define D_ 8
#define B_ 32
#define PRE_ 1024
#define POST_ 1024

// exp(-1/10), exp(-1/20), exp(-1/15)
#define ALPHA_P 0.90483741803595952f
#define ALPHA_D 0.95122942450071400f
#define ALPHA_X 0.93550698503161731f

#define NMAIN (PRE_ * 8)                 // 8192 main blocks: e x bc
#define NFILT (((D_*B_*PRE_)/4 + 2*((B_*POST_)/4)) / 256)   // 320 filter blocks

// Fused kernel.
// Main blocks (bid < 8192): e = bid & 1023, bc = bid >> 10; handles b = 4*bc .. 4*bc+3.
//   Same-e blocks share (bid mod 8) == (e mod 8) -> same XCD -> dmap slice is an L2 hit
//   after the first fetch.
// Tail blocks (bid >= 8192): elementwise exponential-filter outputs.
__global__ __launch_bounds__(256) void clopath_fused(
    const float* __restrict__ W,
    const float* __restrict__ dmap,
    const float* __restrict__ A_p,
    const float* __restrict__ A_d,
    const float* __restrict__ wmax,
    const float* __restrict__ xbar_pre,
    const float* __restrict__ Xd,
    const float* __restrict__ Xpost,
    const float* __restrict__ Vpost,
    const float* __restrict__ u_pot,
    const float* __restrict__ u_dep,
    float* __restrict__ out,       // output 0: copy of W
    float* __restrict__ W_new,     // output 1
    float* __restrict__ xbar_new,  // output 2
    float* __restrict__ u_pot_new, // output 3
    float* __restrict__ u_dep_new) // output 4
{
    const int bid = blockIdx.x;
    const int tid = threadIdx.x;

    if (bid < NMAIN) {
        const int e  = bid & (PRE_ - 1);   // 0..1023
        const int bc = bid >> 10;          // 0..7
        const int b0 = bc << 2;            // first b of this block
        const int o  = tid << 2;           // float4 of POST

        // Stage the 32 block-uniform scalars xbar_pre[d, b0+bi, e], Xd[d, b0+bi, e]
        __shared__ float xb_lds[D_ * 4];
        __shared__ float xd_lds[D_ * 4];
        if (tid < D_ * 4) {
            const int d  = tid >> 2;
            const int bi = tid & 3;
            const size_t idx = ((size_t)(d * B_ + b0 + bi)) * PRE_ + e;
            xb_lds[tid] = xbar_pre[idx];
            xd_lds[tid] = Xd[idx];
        }
        __syncthreads();

        // Preload dmap rows and per-(e,o) factors into registers
        float dmv[D_][4];
        #pragma unroll
        for (int d = 0; d < D_; ++d) {
            float4 t = *reinterpret_cast<const float4*>(
                dmap + ((size_t)(d * PRE_ + e) * POST_ + o));
            dmv[d][0] = t.x; dmv[d][1] = t.y; dmv[d][2] = t.z; dmv[d][3] = t.w;
        }
        float apv[4], adv[4], wmv[4];
        {
            float4 a = *reinterpret_cast<const float4*>(A_p  + ((size_t)e * POST_ + o));
            apv[0] = a.x; apv[1] = a.y; apv[2] = a.z; apv[3] = a.w;
            float4 b = *reinterpret_cast<const float4*>(A_d  + ((size_t)e * POST_ + o));
            adv[0] = b.x; adv[1] = b.y; adv[2] = b.z; adv[3] = b.w;
            float4 c = *reinterpret_cast<const float4*>(wmax + ((size_t)e * POST_ + o));
            wmv[0] = c.x; wmv[1] = c.y; wmv[2] = c.z; wmv[3] = c.w;
        }

        #pragma unroll
        for (int bi = 0; bi < 4; ++bi) {
            const int b = b0 + bi;
            const size_t wi = ((size_t)(b * PRE_ + e)) * POST_ + o;
            const size_t go = (size_t)b * POST_ + o;

            float4 w4  = *reinterpret_cast<const float4*>(W      + wi);
            float4 xp4 = *reinterpret_cast<const float4*>(Xpost  + go);
            float4 up4 = *reinterpret_cast<const float4*>(u_pot  + go);
            float4 ud4 = *reinterpret_cast<const float4*>(u_dep  + go);

            float wv[4]  = {w4.x, w4.y, w4.z, w4.w};
            float xpv[4] = {xp4.x, xp4.y, xp4.z, xp4.w};
            float upv[4] = {up4.x, up4.y, up4.z, up4.w};
            float udv[4] = {ud4.x, ud4.y, ud4.z, ud4.w};

            float sp[4] = {0.f, 0.f, 0.f, 0.f};
            float sd[4] = {0.f, 0.f, 0.f, 0.f};
            #pragma unroll
            for (int d = 0; d < D_; ++d) {
                const float xb = xb_lds[d * 4 + bi];   // uniform address -> broadcast
                const float xd = xd_lds[d * 4 + bi];
                #pragma unroll
                for (int j = 0; j < 4; ++j) {
                    sp[j] = fmaf(xb, dmv[d][j], sp[j]);
                    sd[j] = fmaf(xd, dmv[d][j], sd[j]);
                }
            }

            float ov[4], nv[4];
            #pragma unroll
            for (int j = 0; j < 4; ++j) {
                const float gp = xpv[j] * fmaxf(upv[j], 0.f);  // Xpost * relu(u_pot)
                const float gd = fmaxf(udv[j], 0.f);           // relu(u_dep)
                float wn = wv[j] + sp[j] * apv[j] * gp - sd[j] * adv[j] * gd;
                wn = fminf(wmv[j], fmaxf(wn, 0.f));
                ov[j] = wv[j];
                nv[j] = wn;
            }
            *reinterpret_cast<float4*>(out   + wi) = make_float4(ov[0], ov[1], ov[2], ov[3]);
            *reinterpret_cast<float4*>(W_new + wi) = make_float4(nv[0], nv[1], nv[2], nv[3]);
        }
    } else {
        // ---- filter tail: elementwise exponential filters ----
        const int i = (bid - NMAIN) * 256 + tid;   // float4 index
        const int NX = (D_ * B_ * PRE_) / 4;       // 65536
        const int NU = (B_ * POST_) / 4;           // 8192

        if (i < NX) {
            float4 a = *reinterpret_cast<const float4*>(xbar_pre + (size_t)i * 4);
            float4 b = *reinterpret_cast<const float4*>(Xd       + (size_t)i * 4);
            float4 r;
            r.x = ALPHA_X * a.x + (1.0f - ALPHA_X) * b.x;
            r.y = ALPHA_X * a.y + (1.0f - ALPHA_X) * b.y;
            r.z = ALPHA_X * a.z + (1.0f - ALPHA_X) * b.z;
            r.w = ALPHA_X * a.w + (1.0f - ALPHA_X) * b.w;
            *reinterpret_cast<float4*>(xbar_new + (size_t)i * 4) = r;
        } else if (i < NX + NU) {
            const int j = i - NX;
            float4 a = *reinterpret_cast<const float4*>(u_pot + (size_t)j * 4);
            float4 b = *reinterpret_cast<const float4*>(Vpost + (size_t)j * 4);
            float4 r;
            r.x = ALPHA_P * a.x + (1.0f - ALPHA_P) * b.x;
            r.y = ALPHA_P * a.y + (1.0f - ALPHA_P) * b.y;
            r.z = ALPHA_P * a.z + (1.0f - ALPHA_P) * b.z;
            r.w = ALPHA_P * a.w + (1.0f - ALPHA_P) * b.w;
            *reinterpret_cast<float4*>(u_pot_new + (size_t)j * 4) = r;
        } else {
            const int j = i - NX - NU;
            float4 a = *reinterpret_cast<const float4*>(u_dep + (size_t)j * 4);
            float4 b = *reinterpret_cast<const float4*>(Vpost + (size_t)j * 4);
            float4 r;
            r.x = ALPHA_D * a.x + (1.0f - ALPHA_D) * b.x;
            r.y = ALPHA_D * a.y + (1.0f - ALPHA_D) * b.y;
            r.z = ALPHA_D * a.z + (1.0f - ALPHA_D) * b.z;
            r.w = ALPHA_D * a.w + (1.0f - ALPHA_D) * b.w;
            *reinterpret_cast<float4*>(u_dep_new + (size_t)j * 4) = r;
        }
    }
}

extern "C" void kernel_launch(void* const* d_in, const int* in_sizes, int n_in,
                              void* d_out, int out_size, void* d_ws, size_t ws_size,
                              hipStream_t stream) {
    const float* Xd       = (const float*)d_in[0];
    const float* Xpost    = (const float*)d_in[1];
    const float* Vpost    = (const float*)d_in[2];
    const float* W        = (const float*)d_in[3];
    const float* xbar_pre = (const float*)d_in[4];
    const float* u_pot    = (const float*)d_in[5];
    const float* u_dep    = (const float*)d_in[6];
    const float* dmap     = (const float*)d_in[7];
    const float* A_p      = (const float*)d_in[8];
    const float* A_d      = (const float*)d_in[9];
    const float* wmax     = (const float*)d_in[10];

    float* out        = (float*)d_out;
    float* W_new      = out + (size_t)B_ * PRE_ * POST_;
    float* xbar_new   = W_new + (size_t)B_ * PRE_ * POST_;
    float* u_pot_new  = xbar_new + (size_t)D_ * B_ * PRE_;
    float* u_dep_new  = u_pot_new + (size_t)B_ * POST_;

    clopath_fused<<<NMAIN + NFILT, 256, 0, stream>>>(
        W, dmap, A_p, A_d, wmax, xbar_pre, Xd, Xpost, Vpost, u_pot, u_dep,
        out, W_new, xbar_new, u_pot_new, u_dep_new);
}